// Round 1
// baseline (235.780 us; speedup 1.0000x reference)
//
#include <hip/hip_runtime.h>
#include <hip/hip_bf16.h>

typedef __bf16 bf16;
typedef __bf16 bf16x8 __attribute__((ext_vector_type(8)));
typedef float  f32x4  __attribute__((ext_vector_type(4)));

#define MFMA16(a,b,c) __builtin_amdgcn_mfma_f32_16x16x32_bf16((a),(b),(c),0,0,0)

// Problem constants: B=32, C=E=512, H=W=32 -> S=1024, 8 heads x 64
constexpr int Bn = 32;
constexpr int Cn = 512;
constexpr int Sn = 1024;

// ---------------------------------------------------------------------------
// K0a: x (B,C,S) fp32 -> xbT (B,S,C) bf16   (tiled transpose + convert)
// ---------------------------------------------------------------------------
__global__ __launch_bounds__(256) void k_transpose(const float* __restrict__ x,
                                                   bf16* __restrict__ xbT) {
    int bid = blockIdx.x;            // b*128 + ct*16 + st
    int st = bid & 15;
    int ct = (bid >> 4) & 7;
    int b  = bid >> 7;
    __shared__ bf16 tl[64][72];      // [s_local][c_local], stride 144B (9x16B)
    int t  = threadIdx.x;
    int cr = t >> 2;                 // 0..63 (c row for read)
    int sc = (t & 3) << 4;           // 0,16,32,48 (s chunk)
    const float4* src4 = (const float4*)(x + ((size_t)b * Cn + ct * 64 + cr) * Sn + st * 64 + sc);
    float4 vbuf[4];
#pragma unroll
    for (int q = 0; q < 4; ++q) vbuf[q] = src4[q];
#pragma unroll
    for (int q = 0; q < 4; ++q) {
        tl[sc + q * 4 + 0][cr] = (bf16)vbuf[q].x;
        tl[sc + q * 4 + 1][cr] = (bf16)vbuf[q].y;
        tl[sc + q * 4 + 2][cr] = (bf16)vbuf[q].z;
        tl[sc + q * 4 + 3][cr] = (bf16)vbuf[q].w;
    }
    __syncthreads();
    int sr = t >> 2;                 // s row for write
    int cc = (t & 3) << 4;           // 16-elem chunk of c
    bf16* dst = xbT + ((size_t)b * Sn + st * 64 + sr) * Cn + ct * 64 + cc;
    *(bf16x8*)(dst)     = *(const bf16x8*)&tl[sr][cc];
    *(bf16x8*)(dst + 8) = *(const bf16x8*)&tl[sr][cc + 8];
}

// ---------------------------------------------------------------------------
// K0b: weights fp32 -> bf16, packed [Wq|Wk|Wv|Wo], each 512x512 row-major
// ---------------------------------------------------------------------------
__global__ __launch_bounds__(256) void k_cvt_w(const float* __restrict__ Wq,
                                               const float* __restrict__ Wk,
                                               const float* __restrict__ Wv,
                                               const float* __restrict__ Wo,
                                               bf16* __restrict__ Wb) {
    int tid = blockIdx.x * 256 + threadIdx.x;   // 512 blocks
    int idx = tid * 8;                          // 8 elems/thread
    int mat = idx >> 18;                        // 262144 per matrix
    int off = idx & 262143;
    const float* s = (mat == 0) ? Wq : (mat == 1) ? Wk : (mat == 2) ? Wv : Wo;
    const float4* s4 = (const float4*)(s + off);
    float4 u = s4[0], v = s4[1];
    bf16x8 o;
    o[0] = (bf16)u.x; o[1] = (bf16)u.y; o[2] = (bf16)u.z; o[3] = (bf16)u.w;
    o[4] = (bf16)v.x; o[5] = (bf16)v.y; o[6] = (bf16)v.z; o[7] = (bf16)v.w;
    *(bf16x8*)(Wb + idx) = o;
}

// ---------------------------------------------------------------------------
// K1: per (b,h): KV[d][e] = sum_s phi(K)[d][s] * V[e][s], ksum[d] = sum_s phi(K)[d][s]
//     K^t = Wk_head @ x[b],  V^t = Wv_head @ x[b]  (both 64 x 1024, via MFMA)
//     Writes KVT[bh][e][d] (bf16) and ksum[bh][d] (fp32).
// ---------------------------------------------------------------------------
__global__ __launch_bounds__(256, 1) void k_kv(const bf16* __restrict__ xbT,
                                               const bf16* __restrict__ Wb,
                                               bf16* __restrict__ KVT,
                                               float* __restrict__ ksum) {
    int bh = blockIdx.x;             // b*8 + h
    int h = bh & 7, b = bh >> 3;
    int t = threadIdx.x;
    int lane = t & 63;
    int w = t >> 6;                  // wave 0..3 -> owns rows [16w,16w+16)
    int l15 = lane & 15, g = lane >> 4;

    __shared__ bf16 xT[64][520];     // [s][c] tile, stride 1040B (65x16B)
    __shared__ bf16 pk[64][72];      // phi(K) [d][s]
    __shared__ bf16 vv[64][72];      // V      [e][s]

    // Pin A-fragments of Wk_head / Wv_head in registers for the whole kernel.
    const bf16* Wkb = Wb + 262144 + (size_t)(h * 64 + w * 16 + l15) * 512;
    const bf16* Wvb = Wb + 524288 + (size_t)(h * 64 + w * 16 + l15) * 512;
    bf16x8 ak[16], av[16];
#pragma unroll
    for (int k = 0; k < 16; ++k) {
        ak[k] = *(const bf16x8*)(Wkb + k * 32 + g * 8);
        av[k] = *(const bf16x8*)(Wvb + k * 32 + g * 8);
    }

    f32x4 kv[4];
#pragma unroll
    for (int n = 0; n < 4; ++n) kv[n] = (f32x4){0.f, 0.f, 0.f, 0.f};
    float ks[4] = {0.f, 0.f, 0.f, 0.f};

    const bf16* xb = xbT + (size_t)b * Sn * Cn;

    for (int stile = 0; stile < 16; ++stile) {
        // stage x^T tile [64 s][512 c]
        {
            int sr = t >> 2;
            const bf16* src = xb + (size_t)(stile * 64 + sr) * Cn;
#pragma unroll
            for (int it = 0; it < 16; ++it) {
                int c0 = (t & 3) * 8 + it * 32;
                *(bf16x8*)&xT[sr][c0] = *(const bf16x8*)(src + c0);
            }
        }
        __syncthreads();
        // K and V tiles: D[m=d][n=s] = sum_c W[d][c] x[c][s]
        f32x4 accK[4], accV[4];
#pragma unroll
        for (int n = 0; n < 4; ++n) { accK[n] = (f32x4){0.f,0.f,0.f,0.f}; accV[n] = (f32x4){0.f,0.f,0.f,0.f}; }
#pragma unroll
        for (int k = 0; k < 16; ++k) {
#pragma unroll
            for (int n = 0; n < 4; ++n) {
                bf16x8 bfrag = *(const bf16x8*)&xT[n * 16 + l15][k * 32 + g * 8];
                accK[n] = MFMA16(ak[k], bfrag, accK[n]);
                accV[n] = MFMA16(av[k], bfrag, accV[n]);
            }
        }
        // phi on K, accumulate ksum (on bf16-rounded values for num/denom consistency)
#pragma unroll
        for (int n = 0; n < 4; ++n) {
#pragma unroll
            for (int r = 0; r < 4; ++r) {
                float kvl = accK[n][r];
                kvl = kvl > 0.f ? kvl + 1.f : __expf(kvl);
                bf16 kb = (bf16)kvl;
                ks[r] += (float)kb;
                pk[w * 16 + g * 4 + r][n * 16 + l15] = kb;
                vv[w * 16 + g * 4 + r][n * 16 + l15] = (bf16)accV[n][r];
            }
        }
        __syncthreads();
        // KV += phi(K) @ V^T : m=d, n=e, k=s (s-tile of 64 -> 2 k-steps)
#pragma unroll
        for (int k2 = 0; k2 < 2; ++k2) {
            bf16x8 afrag = *(const bf16x8*)&pk[w * 16 + l15][k2 * 32 + g * 8];
#pragma unroll
            for (int n = 0; n < 4; ++n) {
                bf16x8 bfrag = *(const bf16x8*)&vv[n * 16 + l15][k2 * 32 + g * 8];
                kv[n] = MFMA16(afrag, bfrag, kv[n]);
            }
        }
        __syncthreads();
    }

    // ksum: reduce across the 16 lanes sharing g (they cover s%16), write fp32
#pragma unroll
    for (int r = 0; r < 4; ++r) {
        float v = ks[r];
        v += __shfl_xor(v, 1);
        v += __shfl_xor(v, 2);
        v += __shfl_xor(v, 4);
        v += __shfl_xor(v, 8);
        if (l15 == 0) ksum[bh * 64 + w * 16 + g * 4 + r] = v;
    }
    // KV write, transposed: KVT[bh][e][d]
    bf16* kvo = KVT + (size_t)bh * 4096;
#pragma unroll
    for (int n = 0; n < 4; ++n)
#pragma unroll
        for (int r = 0; r < 4; ++r)
            kvo[(n * 16 + l15) * 64 + w * 16 + g * 4 + r] = (bf16)kv[n][r];
}

// ---------------------------------------------------------------------------
// K2: per (b, s-tile of 64): for each head:
//     phiQ = phi(Wq_h @ x), denom = ksum . phiQ, num = KV^T @ phiQ,
//     O[s][c'] = num/(denom+eps)  -> OT[b][s][c'] (bf16; aliases xbT storage)
// ---------------------------------------------------------------------------
__global__ __launch_bounds__(256, 1) void k_qnum(const bf16* __restrict__ xbT,
                                                 const bf16* __restrict__ Wb,
                                                 const bf16* __restrict__ KVT,
                                                 const float* __restrict__ ksum,
                                                 bf16* __restrict__ OT) {
    int bid = blockIdx.x;            // b*16 + st
    int st = bid & 15, b = bid >> 4;
    int t = threadIdx.x, lane = t & 63, w = t >> 6, l15 = lane & 15, g = lane >> 4;

    __shared__ bf16 xT[64][520];
    __shared__ bf16 pq[64][72];      // phiQ [s][d]
    __shared__ bf16 kvt[64][72];     // KV^T [e][d]
    __shared__ bf16 ot[64][72];      // O    [s][e]
    __shared__ float ksl[64];
    __shared__ float part[64][4];
    __shared__ float rden[64];

    // stage x^T tile (read COMPLETELY before OT (same storage) is written)
    {
        int sr = t >> 2;
        const bf16* src = xbT + ((size_t)b * Sn + st * 64 + sr) * Cn;
#pragma unroll
        for (int it = 0; it < 16; ++it) {
            int c0 = (t & 3) * 8 + it * 32;
            *(bf16x8*)&xT[sr][c0] = *(const bf16x8*)(src + c0);
        }
    }
    __syncthreads();

    for (int h = 0; h < 8; ++h) {
        // Wq_head A-fragments
        const bf16* Wqb = Wb + (size_t)(h * 64 + w * 16 + l15) * 512;
        bf16x8 aq[16];
#pragma unroll
        for (int k = 0; k < 16; ++k) aq[k] = *(const bf16x8*)(Wqb + k * 32 + g * 8);
        // Q tile: D[m=d][n=s]
        f32x4 accQ[4];
#pragma unroll
        for (int n = 0; n < 4; ++n) accQ[n] = (f32x4){0.f,0.f,0.f,0.f};
#pragma unroll
        for (int k = 0; k < 16; ++k) {
#pragma unroll
            for (int n = 0; n < 4; ++n) {
                bf16x8 bfrag = *(const bf16x8*)&xT[n * 16 + l15][k * 32 + g * 8];
                accQ[n] = MFMA16(aq[k], bfrag, accQ[n]);
            }
        }
        // phi -> pq[s][d]
#pragma unroll
        for (int n = 0; n < 4; ++n)
#pragma unroll
            for (int r = 0; r < 4; ++r) {
                float q = accQ[n][r];
                q = q > 0.f ? q + 1.f : __expf(q);
                pq[n * 16 + l15][w * 16 + g * 4 + r] = (bf16)q;
            }
        // stage KV^T and ksum for this head
        {
            int e = t >> 2;
            const bf16* src = KVT + (size_t)(b * 8 + h) * 4096 + e * 64 + (t & 3) * 16;
            *(bf16x8*)&kvt[e][(t & 3) * 16]     = *(const bf16x8*)(src);
            *(bf16x8*)&kvt[e][(t & 3) * 16 + 8] = *(const bf16x8*)(src + 8);
            if (t < 64) ksl[t] = ksum[(b * 8 + h) * 64 + t];
        }
        __syncthreads();
        // denominator partials
        {
            int s = t & 63, q4 = t >> 6;
            float acc = 0.f;
#pragma unroll
            for (int j = 0; j < 16; ++j)
                acc += ksl[q4 * 16 + j] * (float)pq[s][q4 * 16 + j];
            part[s][q4] = acc;
        }
        __syncthreads();
        if (t < 64) {
            float d = part[t][0] + part[t][1] + part[t][2] + part[t][3];
            rden[t] = 1.f / (d + 1e-6f);
        }
        __syncthreads();
        // numerator: D[m=e][n=s] = sum_d KVT[e][d] * pq[s][d]
        f32x4 accN[4];
#pragma unroll
        for (int n = 0; n < 4; ++n) accN[n] = (f32x4){0.f,0.f,0.f,0.f};
#pragma unroll
        for (int k2 = 0; k2 < 2; ++k2) {
            bf16x8 afrag = *(const bf16x8*)&kvt[w * 16 + l15][k2 * 32 + g * 8];
#pragma unroll
            for (int n = 0; n < 4; ++n) {
                bf16x8 bfrag = *(const bf16x8*)&pq[n * 16 + l15][k2 * 32 + g * 8];
                accN[n] = MFMA16(afrag, bfrag, accN[n]);
            }
        }
        // normalize -> ot[s][e]
#pragma unroll
        for (int n = 0; n < 4; ++n) {
            float rd = rden[n * 16 + l15];
#pragma unroll
            for (int r = 0; r < 4; ++r)
                ot[n * 16 + l15][w * 16 + g * 4 + r] = (bf16)(accN[n][r] * rd);
        }
        __syncthreads();
        // cooperative coalesced write of OT[b][s][h*64 .. h*64+63]
        {
            int sr = t >> 2;
            bf16* dst = OT + ((size_t)b * Sn + st * 64 + sr) * Cn + h * 64 + (t & 3) * 16;
            *(bf16x8*)(dst)     = *(const bf16x8*)&ot[sr][(t & 3) * 16];
            *(bf16x8*)(dst + 8) = *(const bf16x8*)&ot[sr][(t & 3) * 16 + 8];
        }
        __syncthreads();
    }
}

// ---------------------------------------------------------------------------
// K3: out[b][co][s] = sum_c' Wo[co][c'] * O[c'][s] + bo[co]   (fp32 out)
// ---------------------------------------------------------------------------
__global__ __launch_bounds__(256, 1) void k_out(const bf16* __restrict__ OT,
                                                const bf16* __restrict__ Wb,
                                                const float* __restrict__ bo,
                                                float* __restrict__ out) {
    int bid = blockIdx.x;            // b*16 + st
    int st = bid & 15, b = bid >> 4;
    int t = threadIdx.x, lane = t & 63, w = t >> 6, l15 = lane & 15, g = lane >> 4;
    __shared__ bf16 oT[64][520];
    __shared__ float bol[512];
    {
        int sr = t >> 2;
        const bf16* src = OT + ((size_t)b * Sn + st * 64 + sr) * Cn;
#pragma unroll
        for (int it = 0; it < 16; ++it) {
            int c0 = (t & 3) * 8 + it * 32;
            *(bf16x8*)&oT[sr][c0] = *(const bf16x8*)(src + c0);
        }
        bol[t] = bo[t];
        bol[t + 256] = bo[t + 256];
    }
    __syncthreads();
    const bf16* Wob = Wb + 786432;
    for (int mt = 0; mt < 8; ++mt) {
        int m0 = w * 128 + mt * 16;
        const bf16* wrow = Wob + (size_t)(m0 + l15) * 512;
        f32x4 acc[4];
#pragma unroll
        for (int n = 0; n < 4; ++n) acc[n] = (f32x4){0.f,0.f,0.f,0.f};
#pragma unroll
        for (int k = 0; k < 16; ++k) {
            bf16x8 afrag = *(const bf16x8*)(wrow + k * 32 + g * 8);
#pragma unroll
            for (int n = 0; n < 4; ++n) {
                bf16x8 bfrag = *(const bf16x8*)&oT[n * 16 + l15][k * 32 + g * 8];
                acc[n] = MFMA16(afrag, bfrag, acc[n]);
            }
        }
#pragma unroll
        for (int r = 0; r < 4; ++r) {
            int co = m0 + g * 4 + r;
            float bb = bol[co];
#pragma unroll
            for (int n = 0; n < 4; ++n)
                out[((size_t)b * Cn + co) * Sn + st * 64 + n * 16 + l15] = acc[n][r] + bb;
        }
    }
}

// ---------------------------------------------------------------------------
extern "C" void kernel_launch(void* const* d_in, const int* in_sizes, int n_in,
                              void* d_out, int out_size, void* d_ws, size_t ws_size,
                              hipStream_t stream) {
    const float* x  = (const float*)d_in[0];
    const float* Wq = (const float*)d_in[1];
    const float* Wk = (const float*)d_in[2];
    const float* Wv = (const float*)d_in[3];
    const float* Wo = (const float*)d_in[4];
    const float* bo = (const float*)d_in[5];
    float* out = (float*)d_out;

    char* ws = (char*)d_ws;
    bf16*  xbT = (bf16*)ws;                      // 33,554,432 B  (B*S*C bf16)
    bf16*  Wb  = (bf16*)(ws + 33554432);         //  2,097,152 B  (4 x 512 x 512 bf16)
    bf16*  KVT = (bf16*)(ws + 35651584);         //  2,097,152 B  (256 x 64 x 64 bf16)
    float* ks  = (float*)(ws + 37748736);        //     65,536 B  (256 x 64 fp32)
    bf16*  OT  = xbT;                            // aliases xbT (safe: K2 reads its
                                                 // tile into LDS before writing)

    k_transpose<<<4096, 256, 0, stream>>>(x, xbT);
    k_cvt_w   <<< 512, 256, 0, stream>>>(Wq, Wk, Wv, Wo, Wb);
    k_kv      <<< 256, 256, 0, stream>>>(xbT, Wb, KVT, ks);
    k_qnum    <<< 512, 256, 0, stream>>>(xbT, Wb, KVT, ks, OT);
    k_out     <<< 512, 256, 0, stream>>>(OT, Wb, bo, out);
}